// Round 3
// baseline (958.789 us; speedup 1.0000x reference)
//
#include <hip/hip_runtime.h>

#define BB 8
#define TT 1024
#define EE 512
#define HH 8
#define HEE 4096

typedef unsigned short u16;
typedef __bf16 bf16x8 __attribute__((ext_vector_type(8)));
typedef float floatx4 __attribute__((ext_vector_type(4)));

__device__ __forceinline__ u16 f2bf(float f) {
    union { float f; unsigned int i; } v; v.f = f;
    unsigned int x = v.i;
    x += 0x7fffu + ((x >> 16) & 1u);   // RNE
    return (u16)(x >> 16);
}
__device__ __forceinline__ float bf2f(u16 u) {
    union { unsigned int i; float f; } v; v.i = ((unsigned int)u) << 16; return v.f;
}

// ---------------------------------------------------------------------------
// K-1: convert x (fp32) -> xbf (bf16), 8 elems/thread
// ---------------------------------------------------------------------------
__global__ __launch_bounds__(256) void convx_kernel(
    const float* __restrict__ x, u16* __restrict__ xb)
{
    size_t i = ((size_t)blockIdx.x * 256 + threadIdx.x) * 8;
    float4 a = *(const float4*)&x[i];
    float4 b = *(const float4*)&x[i + 4];
    union { u16 s[8]; uint4 v; } t;
    t.s[0] = f2bf(a.x); t.s[1] = f2bf(a.y); t.s[2] = f2bf(a.z); t.s[3] = f2bf(a.w);
    t.s[4] = f2bf(b.x); t.s[5] = f2bf(b.y); t.s[6] = f2bf(b.z); t.s[7] = f2bf(b.w);
    *(uint4*)&xb[i] = t.v;
}

// ---------------------------------------------------------------------------
// K0: fused convert(fp32->bf16) + transpose of weights.
// z=0: Wq(512,4096)->WtQ(4096,512); z=1: Wk; z=2: Wh(512,512)->Wht
// ---------------------------------------------------------------------------
__global__ __launch_bounds__(256) void transpose_kernel(
    const float* __restrict__ Wq, const float* __restrict__ Wk, const float* __restrict__ Wh,
    u16* __restrict__ WtQ, u16* __restrict__ WtK, u16* __restrict__ Wht)
{
    int z = blockIdx.z;
    const float* src; u16* dst; int Ndim;
    if (z == 0)      { src = Wq; dst = WtQ; Ndim = HEE; }
    else if (z == 1) { src = Wk; dst = WtK; Ndim = HEE; }
    else             { src = Wh; dst = Wht; Ndim = EE;  }
    int n0 = blockIdx.x << 6, k0 = blockIdx.y << 6;
    if (n0 >= Ndim) return;
    __shared__ u16 tile[64][72];
    int tid = threadIdx.x;
    for (int rep = 0; rep < 4; rep++) {
        int lin = tid + (rep << 8);
        int r = lin >> 4, c4 = (lin & 15) << 2;
        float4 v = *(const float4*)&src[(size_t)(k0 + r) * Ndim + n0 + c4];
        union { u16 s[4]; uint2 u; } t;
        t.s[0] = f2bf(v.x); t.s[1] = f2bf(v.y); t.s[2] = f2bf(v.z); t.s[3] = f2bf(v.w);
        *(uint2*)&tile[r][c4] = t.u;
    }
    __syncthreads();
    for (int rep = 0; rep < 2; rep++) {
        int lin = tid + (rep << 8);
        int rr = lin >> 3, cc8 = (lin & 7) << 3;
        union { u16 s[8]; uint4 v; } tmp;
        #pragma unroll
        for (int u2 = 0; u2 < 8; u2++) tmp.s[u2] = tile[cc8 + u2][rr];
        *(uint4*)&dst[(size_t)(n0 + rr) * EE + k0 + cc8] = tmp.v;
    }
}

// ---------------------------------------------------------------------------
// zero the w accumulator (BB*HH*TT floats)
// ---------------------------------------------------------------------------
__global__ __launch_bounds__(256) void zero_kernel(float* __restrict__ w)
{
    w[blockIdx.x * 256 + threadIdx.x] = 0.f;
}

// ---------------------------------------------------------------------------
// K1: per-batch Q/K projection. out[(h,t,e)] = (x_b @ W + bias) * norm, bf16.
// 128x128 tile, K-step 32, mfma_f32_16x16x32_bf16, 4 waves of 64x64.
// ---------------------------------------------------------------------------
__global__ __launch_bounds__(256) void qk_proj(
    const u16* __restrict__ xb, const u16* __restrict__ WtQ, const u16* __restrict__ WtK,
    const float* __restrict__ bq, const float* __restrict__ bk,
    u16* __restrict__ Qb, u16* __restrict__ Kb, float scale)
{
    const u16* Wt     = blockIdx.z ? WtK : WtQ;
    const float* bias = blockIdx.z ? bk  : bq;
    u16* out          = blockIdx.z ? Kb  : Qb;
    __shared__ u16 As[128][40];   // [m][k] pad 8
    __shared__ u16 Bs[128][40];   // [n][k] pad 8
    int tid = threadIdx.x;
    int n0 = blockIdx.x << 7, m0 = blockIdx.y << 7;
    int w = tid >> 6, lane = tid & 63;
    int g = lane >> 4, mn = lane & 15;
    int wm = (w >> 1) << 6, wn = (w & 1) << 6;
    floatx4 acc[4][4];
    floatx4 zero = {0.f, 0.f, 0.f, 0.f};
    for (int i = 0; i < 4; i++) for (int j = 0; j < 4; j++) acc[i][j] = zero;

    for (int kk = 0; kk < EE; kk += 32) {
        __syncthreads();
        for (int rep = 0; rep < 2; rep++) {
            int lin = tid + (rep << 8);
            int row = lin >> 2, c8 = (lin & 3) << 3;
            *(uint4*)&As[row][c8] = *(const uint4*)&xb[(size_t)(m0 + row) * EE + kk + c8];
            *(uint4*)&Bs[row][c8] = *(const uint4*)&Wt[(size_t)(n0 + row) * EE + kk + c8];
        }
        __syncthreads();
        bf16x8 af[4], bfr[4];
        #pragma unroll
        for (int i = 0; i < 4; i++) af[i]  = *(const bf16x8*)&As[wm + (i << 4) + mn][g << 3];
        #pragma unroll
        for (int j = 0; j < 4; j++) bfr[j] = *(const bf16x8*)&Bs[wn + (j << 4) + mn][g << 3];
        #pragma unroll
        for (int i = 0; i < 4; i++)
            #pragma unroll
            for (int j = 0; j < 4; j++)
                acc[i][j] = __builtin_amdgcn_mfma_f32_16x16x32_bf16(af[i], bfr[j], acc[i][j], 0, 0, 0);
    }
    // epilogue: D row=(lane>>4)*4+r, col=lane&15
    #pragma unroll
    for (int i = 0; i < 4; i++)
        #pragma unroll
        for (int j = 0; j < 4; j++) {
            int col = n0 + wn + (j << 4) + mn;
            int h = col >> 9, e = col & 511;
            float bv = bias[col];
            #pragma unroll
            for (int r = 0; r < 4; r++) {
                int t = m0 + wm + (i << 4) + (g << 2) + r;
                float v = (acc[i][j][r] + bv) * scale;
                out[((size_t)h * TT + t) * EE + e] = f2bf(v);
            }
        }
}

// ---------------------------------------------------------------------------
// K2: attention (one batch). Per workgroup: one h, 16 q-rows. 4 waves each own
// a 256-wide k-quarter. S = Q K^T via MFMA, U=exp(S)->LDS bf16, row sums via
// shuffle, then column sums (divided by row sums) atomicAdd'ed into wb[h][t].
// ---------------------------------------------------------------------------
__global__ __launch_bounds__(256) void attn_kernel(
    const u16* __restrict__ Qb, const u16* __restrict__ Kb, float* __restrict__ wb)
{
    __shared__ u16 Qs[16][520];
    __shared__ u16 U[16][1032];
    __shared__ float lsum[16];
    int tid = threadIdx.x;
    int q0 = blockIdx.x << 4;
    int h = blockIdx.y;
    const u16* Qp = Qb + ((size_t)h * TT + q0) * EE;
    const u16* Kp = Kb + (size_t)h * TT * EE;
    if (tid < 16) lsum[tid] = 0.f;
    for (int rep = 0; rep < 4; rep++) {
        int lin = tid + (rep << 8);
        int row = lin >> 6, c8 = (lin & 63) << 3;
        *(uint4*)&Qs[row][c8] = *(const uint4*)&Qp[(size_t)row * EE + c8];
    }
    __syncthreads();
    int w = tid >> 6, lane = tid & 63;
    int g = lane >> 4, nn = lane & 15;
    for (int kt = 0; kt < 16; kt++) {
        int k0 = (w << 8) + (kt << 4);
        const u16* Krow = Kp + (size_t)(k0 + nn) * EE + (g << 3);
        floatx4 acc = {0.f, 0.f, 0.f, 0.f};
        #pragma unroll
        for (int ee = 0; ee < EE; ee += 32) {
            bf16x8 a = *(const bf16x8*)&Qs[nn][ee + (g << 3)];
            bf16x8 b = *(const bf16x8*)&Krow[ee];
            acc = __builtin_amdgcn_mfma_f32_16x16x32_bf16(a, b, acc, 0, 0, 0);
        }
        float u[4], us[4];
        #pragma unroll
        for (int r = 0; r < 4; r++) { u[r] = __expf(acc[r]); us[r] = u[r]; }
        #pragma unroll
        for (int r = 0; r < 4; r++) U[(g << 2) + r][k0 + nn] = f2bf(u[r]);
        #pragma unroll
        for (int off = 1; off < 16; off <<= 1) {
            #pragma unroll
            for (int r = 0; r < 4; r++) us[r] += __shfl_xor(us[r], off, 64);
        }
        if (nn == 0) {
            #pragma unroll
            for (int r = 0; r < 4; r++) atomicAdd(&lsum[(g << 2) + r], us[r]);
        }
    }
    __syncthreads();
    float linv[16];
    #pragma unroll
    for (int r = 0; r < 16; r++) linv[r] = 1.f / lsum[r];
    float* wp = wb + (size_t)h * TT;
    for (int cc = tid; cc < TT; cc += 256) {
        float s = 0.f;
        #pragma unroll
        for (int r = 0; r < 16; r++) s += bf2f(U[r][cc]) * linv[r];
        atomicAdd(&wp[cc], s);
    }
}

// ---------------------------------------------------------------------------
// K3a: sV[b,h,:] = sum_k w[b,h,k] * x[b,k,:]   (x fp32)
// ---------------------------------------------------------------------------
__global__ __launch_bounds__(256) void sv_kernel(
    const float* __restrict__ x, const float* __restrict__ w, float* __restrict__ sV)
{
    __shared__ float wl[TT];
    int bh = blockIdx.x, b = bh >> 3;
    int tid = threadIdx.x;
    const float* wp = w + (size_t)bh * TT;
    for (int c = tid; c < TT; c += 256) wl[c] = wp[c];
    __syncthreads();
    const float* xb = x + (size_t)b * TT * EE;
    float a00 = 0, a01 = 0, a10 = 0, a11 = 0;
    for (int k = 0; k < TT; k += 2) {
        float w0 = wl[k], w1 = wl[k + 1];
        const float* x0 = xb + (size_t)k * EE;
        a00 += w0 * x0[tid];
        a01 += w0 * x0[tid + 256];
        a10 += w1 * x0[EE + tid];
        a11 += w1 * x0[EE + tid + 256];
    }
    sV[(size_t)bh * EE + tid]       = a00 + a10;
    sV[(size_t)bh * EE + tid + 256] = a01 + a11;
}

// ---------------------------------------------------------------------------
// K3b: out1[b, h*512+e] = sV[b,h,:] @ Wv[:, h*512+e] + 1024*bv  (sum_k w_k=T)
// ---------------------------------------------------------------------------
__global__ __launch_bounds__(256) void out1_kernel(
    const float* __restrict__ sV, const float* __restrict__ Wv,
    const float* __restrict__ bv, float* __restrict__ o1)
{
    int bh = blockIdx.x, b = bh >> 3, h = bh & 7;
    int tid = threadIdx.x;
    const float* s = sV + (size_t)bh * EE;
    float a00 = 0, a01 = 0, a10 = 0, a11 = 0;
    for (int e2 = 0; e2 < EE; e2 += 2) {
        float s0 = s[e2], s1 = s[e2 + 1];
        const float* w0 = Wv + (size_t)e2 * HEE + (h << 9);
        const float* w1 = w0 + HEE;
        a00 += s0 * w0[tid];       a01 += s0 * w0[tid + 256];
        a10 += s1 * w1[tid];       a11 += s1 * w1[tid + 256];
    }
    float r0 = a00 + a10 + 1024.f * bv[(h << 9) + tid];
    float r1 = a01 + a11 + 1024.f * bv[(h << 9) + tid + 256];
    o1[(size_t)b * HEE + (h << 9) + tid]       = r0;
    o1[(size_t)b * HEE + (h << 9) + tid + 256] = r1;
}

// ---------------------------------------------------------------------------
// K3c: out2[b,e] = relu(out1[b,:] @ Wu[:,e] + bu[e])
// ---------------------------------------------------------------------------
__global__ __launch_bounds__(512) void out2_kernel(
    const float* __restrict__ o1, const float* __restrict__ Wu,
    const float* __restrict__ bu, float* __restrict__ o2)
{
    int b = blockIdx.x, e = threadIdx.x;
    const float* o = o1 + (size_t)b * HEE;
    float a[8] = {0, 0, 0, 0, 0, 0, 0, 0};
    for (int j0 = 0; j0 < HEE; j0 += 8) {
        #pragma unroll
        for (int u2 = 0; u2 < 8; u2++)
            a[u2] += o[j0 + u2] * Wu[(size_t)(j0 + u2) * EE + e];
    }
    float r = a[0] + a[1] + a[2] + a[3] + a[4] + a[5] + a[6] + a[7] + bu[e];
    o2[(size_t)b * EE + e] = fmaxf(r, 0.f);
}

// ---------------------------------------------------------------------------
// K4: LN1 over rows of (x + out2 broadcast) -> y1 bf16
// ---------------------------------------------------------------------------
__global__ __launch_bounds__(256) void ln1_kernel(
    const float* __restrict__ x, const float* __restrict__ o2,
    const float* __restrict__ gg, const float* __restrict__ bb, u16* __restrict__ y)
{
    int row = blockIdx.x, b = row >> 10;
    int tid = threadIdx.x;
    const float* xr = x + (size_t)row * EE;
    const float* ob = o2 + (size_t)b * EE;
    float v0 = xr[tid] + ob[tid];
    float v1 = xr[tid + 256] + ob[tid + 256];
    float s = v0 + v1, q = v0 * v0 + v1 * v1;
    for (int off = 1; off < 64; off <<= 1) { s += __shfl_xor(s, off, 64); q += __shfl_xor(q, off, 64); }
    __shared__ float rs[4], rq[4];
    int w = tid >> 6, ln = tid & 63;
    if (ln == 0) { rs[w] = s; rq[w] = q; }
    __syncthreads();
    s = rs[0] + rs[1] + rs[2] + rs[3];
    q = rq[0] + rq[1] + rq[2] + rq[3];
    float mean = s * (1.f / EE);
    float var = q * (1.f / EE) - mean * mean;
    float rstd = rsqrtf(var + 1e-5f);
    y[(size_t)row * EE + tid]       = f2bf((v0 - mean) * rstd * gg[tid]       + bb[tid]);
    y[(size_t)row * EE + tid + 256] = f2bf((v1 - mean) * rstd * gg[tid + 256] + bb[tid + 256]);
}

// ---------------------------------------------------------------------------
// K5: z = y1 + relu(y1 @ Wh + bh)   (128x128 tile GEMM, N=512), bf16 out
// ---------------------------------------------------------------------------
__global__ __launch_bounds__(256) void ffn_gemm(
    const u16* __restrict__ A, const u16* __restrict__ Wt,
    const float* __restrict__ bias, u16* __restrict__ Z)
{
    __shared__ u16 As[128][40];
    __shared__ u16 Bs[128][40];
    int tid = threadIdx.x;
    int n0 = blockIdx.x << 7, m0 = blockIdx.y << 7;
    int w = tid >> 6, lane = tid & 63;
    int g = lane >> 4, mn = lane & 15;
    int wm = (w >> 1) << 6, wn = (w & 1) << 6;
    floatx4 acc[4][4];
    floatx4 zero = {0.f, 0.f, 0.f, 0.f};
    for (int i = 0; i < 4; i++) for (int j = 0; j < 4; j++) acc[i][j] = zero;

    for (int kk = 0; kk < EE; kk += 32) {
        __syncthreads();
        for (int rep = 0; rep < 2; rep++) {
            int lin = tid + (rep << 8);
            int row = lin >> 2, c8 = (lin & 3) << 3;
            *(uint4*)&As[row][c8] = *(const uint4*)&A [(size_t)(m0 + row) * EE + kk + c8];
            *(uint4*)&Bs[row][c8] = *(const uint4*)&Wt[(size_t)(n0 + row) * EE + kk + c8];
        }
        __syncthreads();
        bf16x8 af[4], bfr[4];
        #pragma unroll
        for (int i = 0; i < 4; i++) af[i]  = *(const bf16x8*)&As[wm + (i << 4) + mn][g << 3];
        #pragma unroll
        for (int j = 0; j < 4; j++) bfr[j] = *(const bf16x8*)&Bs[wn + (j << 4) + mn][g << 3];
        #pragma unroll
        for (int i = 0; i < 4; i++)
            #pragma unroll
            for (int j = 0; j < 4; j++)
                acc[i][j] = __builtin_amdgcn_mfma_f32_16x16x32_bf16(af[i], bfr[j], acc[i][j], 0, 0, 0);
    }
    #pragma unroll
    for (int i = 0; i < 4; i++)
        #pragma unroll
        for (int j = 0; j < 4; j++) {
            int col = n0 + wn + (j << 4) + mn;
            float bv = bias[col];
            #pragma unroll
            for (int r = 0; r < 4; r++) {
                int row = m0 + wm + (i << 4) + (g << 2) + r;
                float v = fmaxf(acc[i][j][r] + bv, 0.f) + bf2f(A[(size_t)row * EE + col]);
                Z[(size_t)row * EE + col] = f2bf(v);
            }
        }
}

// ---------------------------------------------------------------------------
// K6: LN2 over rows of z (bf16) -> d_out fp32
// ---------------------------------------------------------------------------
__global__ __launch_bounds__(256) void ln2_kernel(
    const u16* __restrict__ z, const float* __restrict__ gg,
    const float* __restrict__ bb, float* __restrict__ y)
{
    int row = blockIdx.x;
    int tid = threadIdx.x;
    const u16* zr = z + (size_t)row * EE;
    float v0 = bf2f(zr[tid]);
    float v1 = bf2f(zr[tid + 256]);
    float s = v0 + v1, q = v0 * v0 + v1 * v1;
    for (int off = 1; off < 64; off <<= 1) { s += __shfl_xor(s, off, 64); q += __shfl_xor(q, off, 64); }
    __shared__ float rs[4], rq[4];
    int w = tid >> 6, ln = tid & 63;
    if (ln == 0) { rs[w] = s; rq[w] = q; }
    __syncthreads();
    s = rs[0] + rs[1] + rs[2] + rs[3];
    q = rq[0] + rq[1] + rq[2] + rq[3];
    float mean = s * (1.f / EE);
    float var = q * (1.f / EE) - mean * mean;
    float rstd = rsqrtf(var + 1e-5f);
    y[(size_t)row * EE + tid]       = (v0 - mean) * rstd * gg[tid]       + bb[tid];
    y[(size_t)row * EE + tid + 256] = (v1 - mean) * rstd * gg[tid + 256] + bb[tid + 256];
}

// ---------------------------------------------------------------------------
extern "C" void kernel_launch(void* const* d_in, const int* in_sizes, int n_in,
                              void* d_out, int out_size, void* d_ws, size_t ws_size,
                              hipStream_t stream)
{
    const float* x  = (const float*)d_in[0];
    const float* Wq = (const float*)d_in[1];
    const float* bq = (const float*)d_in[2];
    const float* Wk = (const float*)d_in[3];
    const float* bk = (const float*)d_in[4];
    const float* Wv = (const float*)d_in[5];
    const float* bv = (const float*)d_in[6];
    const float* Wu = (const float*)d_in[7];
    const float* bu = (const float*)d_in[8];
    const float* g1 = (const float*)d_in[9];
    const float* b1 = (const float*)d_in[10];
    const float* Wh = (const float*)d_in[11];
    const float* bh = (const float*)d_in[12];
    const float* g2 = (const float*)d_in[13];
    const float* b2 = (const float*)d_in[14];
    float* out = (float*)d_out;

    // workspace layout — peak ~33 MB
    char* p = (char*)d_ws;
    u16* WtQ = (u16*)p;  p += (size_t)HEE * EE * 2;           //  4   MB
    u16* WtK = (u16*)p;  p += (size_t)HEE * EE * 2;           //  4   MB
    u16* Wht = (u16*)p;  p += (size_t)EE * EE * 2;            //  0.5 MB
    u16* xbf = (u16*)p;  p += (size_t)BB * TT * EE * 2;       //  8   MB
    u16* Qb  = (u16*)p;  p += (size_t)HH * TT * EE * 2;       //  8   MB (per-batch; later y1)
    u16* Kb  = (u16*)p;  p += (size_t)HH * TT * EE * 2;       //  8   MB (per-batch; later zz)
    float* w   = (float*)p; p += (size_t)BB * HH * TT * 4;    //  0.25 MB
    float* sV  = (float*)p; p += (size_t)BB * HH * EE * 4;    //  0.125 MB
    float* o1  = (float*)p; p += (size_t)BB * HEE * 4;        //  0.125 MB
    float* o2  = (float*)p; p += (size_t)BB * EE * 4;         //  16 KB
    u16* y1 = Qb;   // overlay: Q dead after attention loop
    u16* zz = Kb;   // overlay: K dead after attention loop

    const float norm = 0.04419417382415922f;  // 1/sqrt(512)

    convx_kernel<<<dim3(2048), 256, 0, stream>>>(x, xbf);
    transpose_kernel<<<dim3(64, 8, 3), 256, 0, stream>>>(Wq, Wk, Wh, WtQ, WtK, Wht);
    zero_kernel<<<dim3(BB * HH * TT / 256), 256, 0, stream>>>(w);
    for (int b = 0; b < BB; b++) {
        qk_proj<<<dim3(32, 8, 2), 256, 0, stream>>>(
            xbf + (size_t)b * TT * EE, WtQ, WtK, bq, bk, Qb, Kb, norm);
        attn_kernel<<<dim3(64, 8), 256, 0, stream>>>(Qb, Kb, w + (size_t)b * HH * TT);
    }
    sv_kernel<<<dim3(64), 256, 0, stream>>>(x, w, sV);
    out1_kernel<<<dim3(64), 256, 0, stream>>>(sV, Wv, bv, o1);
    out2_kernel<<<dim3(8), 512, 0, stream>>>(o1, Wu, bu, o2);
    ln1_kernel<<<dim3(8192), 256, 0, stream>>>(x, o2, g1, b1, y1);
    ffn_gemm<<<dim3(4, 64), 256, 0, stream>>>(y1, Wht, bh, zz);
    ln2_kernel<<<dim3(8192), 256, 0, stream>>>(zz, g2, b2, out);
}

// Round 4
// 611.268 us; speedup vs baseline: 1.5685x; 1.5685x over previous
//
#include <hip/hip_runtime.h>

#define BB 8
#define TT 1024
#define EE 512
#define HH 8
#define HEE 4096

typedef unsigned short u16;
typedef __bf16 bf16x8 __attribute__((ext_vector_type(8)));
typedef float floatx4 __attribute__((ext_vector_type(4)));
typedef float floatx16 __attribute__((ext_vector_type(16)));

__device__ __forceinline__ u16 f2bf(float f) {
    union { float f; unsigned int i; } v; v.f = f;
    unsigned int x = v.i;
    x += 0x7fffu + ((x >> 16) & 1u);   // RNE
    return (u16)(x >> 16);
}
__device__ __forceinline__ float bf2f(u16 u) {
    union { unsigned int i; float f; } v; v.i = ((unsigned int)u) << 16; return v.f;
}
__device__ __forceinline__ unsigned int pack2(float a, float b) {
    return (unsigned int)f2bf(a) | ((unsigned int)f2bf(b) << 16);
}

// ---------------------------------------------------------------------------
// convert x (fp32) -> xbf (bf16), 8 elems/thread
// ---------------------------------------------------------------------------
__global__ __launch_bounds__(256) void convx_kernel(
    const float* __restrict__ x, u16* __restrict__ xb)
{
    size_t i = ((size_t)blockIdx.x * 256 + threadIdx.x) * 8;
    float4 a = *(const float4*)&x[i];
    float4 b = *(const float4*)&x[i + 4];
    union { u16 s[8]; uint4 v; } t;
    t.s[0] = f2bf(a.x); t.s[1] = f2bf(a.y); t.s[2] = f2bf(a.z); t.s[3] = f2bf(a.w);
    t.s[4] = f2bf(b.x); t.s[5] = f2bf(b.y); t.s[6] = f2bf(b.z); t.s[7] = f2bf(b.w);
    *(uint4*)&xb[i] = t.v;
}

// ---------------------------------------------------------------------------
// fused convert(fp32->bf16) + transpose of weights.
// z=0: Wq(512,4096)->WtQ(4096,512); z=1: Wk; z=2: Wh(512,512)->Wht
// ---------------------------------------------------------------------------
__global__ __launch_bounds__(256) void transpose_kernel(
    const float* __restrict__ Wq, const float* __restrict__ Wk, const float* __restrict__ Wh,
    u16* __restrict__ WtQ, u16* __restrict__ WtK, u16* __restrict__ Wht)
{
    int z = blockIdx.z;
    const float* src; u16* dst; int Ndim;
    if (z == 0)      { src = Wq; dst = WtQ; Ndim = HEE; }
    else if (z == 1) { src = Wk; dst = WtK; Ndim = HEE; }
    else             { src = Wh; dst = Wht; Ndim = EE;  }
    int n0 = blockIdx.x << 6, k0 = blockIdx.y << 6;
    if (n0 >= Ndim) return;
    __shared__ u16 tile[64][72];
    int tid = threadIdx.x;
    for (int rep = 0; rep < 4; rep++) {
        int lin = tid + (rep << 8);
        int r = lin >> 4, c4 = (lin & 15) << 2;
        float4 v = *(const float4*)&src[(size_t)(k0 + r) * Ndim + n0 + c4];
        union { u16 s[4]; uint2 u; } t;
        t.s[0] = f2bf(v.x); t.s[1] = f2bf(v.y); t.s[2] = f2bf(v.z); t.s[3] = f2bf(v.w);
        *(uint2*)&tile[r][c4] = t.u;
    }
    __syncthreads();
    for (int rep = 0; rep < 2; rep++) {
        int lin = tid + (rep << 8);
        int rr = lin >> 3, cc8 = (lin & 7) << 3;
        union { u16 s[8]; uint4 v; } tmp;
        #pragma unroll
        for (int u2 = 0; u2 < 8; u2++) tmp.s[u2] = tile[cc8 + u2][rr];
        *(uint4*)&dst[(size_t)(n0 + rr) * EE + k0 + cc8] = tmp.v;
    }
}

// ---------------------------------------------------------------------------
// Q/K projection. out[(bl,h,t,e)] = (x @ W + bias) * norm, bf16.
// 128x128 tile, K-step 32, mfma_f32_16x16x32_bf16. grid (32, nb*8, 2).
// ---------------------------------------------------------------------------
__global__ __launch_bounds__(256) void qk_proj(
    const u16* __restrict__ xb, const u16* __restrict__ WtQ, const u16* __restrict__ WtK,
    const float* __restrict__ bq, const float* __restrict__ bk,
    u16* __restrict__ Qb, u16* __restrict__ Kb, float scale)
{
    const u16* Wt     = blockIdx.z ? WtK : WtQ;
    const float* bias = blockIdx.z ? bk  : bq;
    u16* out          = blockIdx.z ? Kb  : Qb;
    __shared__ u16 As[128][40];
    __shared__ u16 Bs[128][40];
    int tid = threadIdx.x;
    int n0 = blockIdx.x << 7, m0 = blockIdx.y << 7;
    int w = tid >> 6, lane = tid & 63;
    int g = lane >> 4, mn = lane & 15;
    int wm = (w >> 1) << 6, wn = (w & 1) << 6;
    floatx4 acc[4][4];
    floatx4 zero = {0.f, 0.f, 0.f, 0.f};
    for (int i = 0; i < 4; i++) for (int j = 0; j < 4; j++) acc[i][j] = zero;

    for (int kk = 0; kk < EE; kk += 32) {
        __syncthreads();
        for (int rep = 0; rep < 2; rep++) {
            int lin = tid + (rep << 8);
            int row = lin >> 2, c8 = (lin & 3) << 3;
            *(uint4*)&As[row][c8] = *(const uint4*)&xb[(size_t)(m0 + row) * EE + kk + c8];
            *(uint4*)&Bs[row][c8] = *(const uint4*)&Wt[(size_t)(n0 + row) * EE + kk + c8];
        }
        __syncthreads();
        bf16x8 af[4], bfr[4];
        #pragma unroll
        for (int i = 0; i < 4; i++) af[i]  = *(const bf16x8*)&As[wm + (i << 4) + mn][g << 3];
        #pragma unroll
        for (int j = 0; j < 4; j++) bfr[j] = *(const bf16x8*)&Bs[wn + (j << 4) + mn][g << 3];
        #pragma unroll
        for (int i = 0; i < 4; i++)
            #pragma unroll
            for (int j = 0; j < 4; j++)
                acc[i][j] = __builtin_amdgcn_mfma_f32_16x16x32_bf16(af[i], bfr[j], acc[i][j], 0, 0, 0);
    }
    #pragma unroll
    for (int i = 0; i < 4; i++)
        #pragma unroll
        for (int j = 0; j < 4; j++) {
            int col = n0 + wn + (j << 4) + mn;
            int h = col >> 9, e = col & 511;
            float bv = bias[col];
            #pragma unroll
            for (int r = 0; r < 4; r++) {
                int row = m0 + wm + (i << 4) + (g << 2) + r;
                int bl = row >> 10, t = row & 1023;
                float v = (acc[i][j][r] + bv) * scale;
                out[(((size_t)bl * HH + h) * TT + t) * EE + e] = f2bf(v);
            }
        }
}

// ---------------------------------------------------------------------------
// attention: grid (32 qtiles, 8 h, nb). Block: 32 q-rows, 4 waves splitting
// the k-range (4 x 256). mfma_f32_32x32x16_bf16: per wave 8 k-tiles of 32.
// exp(S) kept packed-bf16 in 64 VGPRs; rowsums shuffle+LDS; colsums
// shfl_xor(32); per-block column partials -> wpart (no atomics).
// C/D map: col=lane&31, row=(reg&3)+8*(reg>>2)+4*(lane>>5)
// ---------------------------------------------------------------------------
__global__ __launch_bounds__(256) void attn_kernel(
    const u16* __restrict__ Qb, const u16* __restrict__ Kb, float* __restrict__ wpart)
{
    __shared__ u16 Qs[32][520];
    __shared__ float rsum[4][32];
    __shared__ float wcol[1024];
    int tid = threadIdx.x;
    int qt = blockIdx.x, h = blockIdx.y, bl = blockIdx.z;
    const u16* Qp = Qb + (((size_t)bl * HH + h) * TT + (qt << 5)) * EE;
    const u16* Kp = Kb + ((size_t)bl * HH + h) * TT * EE;
    for (int rep = 0; rep < 8; rep++) {
        int lin = tid + (rep << 8);
        int row = lin >> 6, c8 = (lin & 63) << 3;
        *(uint4*)&Qs[row][c8] = *(const uint4*)&Qp[(size_t)row * EE + c8];
    }
    __syncthreads();
    int w = tid >> 6, lane = tid & 63;
    int l31 = lane & 31, l5 = lane >> 5;
    int aoff = l5 << 3;
    unsigned int upk[8][8];
    float rsl[16];
    #pragma unroll
    for (int i = 0; i < 16; i++) rsl[i] = 0.f;

    for (int kt = 0; kt < 8; kt++) {
        int k0 = (w << 8) + (kt << 5);
        const u16* Krow = Kp + (size_t)(k0 + l31) * EE + aoff;
        floatx16 acc;
        #pragma unroll
        for (int i = 0; i < 16; i++) acc[i] = 0.f;
        #pragma unroll
        for (int ee = 0; ee < EE; ee += 16) {
            bf16x8 b = *(const bf16x8*)&Krow[ee];
            bf16x8 a = *(const bf16x8*)&Qs[l31][ee + aoff];
            acc = __builtin_amdgcn_mfma_f32_32x32x16_bf16(a, b, acc, 0, 0, 0);
        }
        #pragma unroll
        for (int pr = 0; pr < 8; pr++) {
            float u0 = __expf(acc[2 * pr]);
            float u1 = __expf(acc[2 * pr + 1]);
            rsl[2 * pr]     += u0;
            rsl[2 * pr + 1] += u1;
            upk[kt][pr] = pack2(u0, u1);
        }
    }
    // rowsum: reduce over the 32 columns (lanes sharing l5)
    #pragma unroll
    for (int i = 0; i < 16; i++) {
        float v = rsl[i];
        v += __shfl_xor(v, 1, 64); v += __shfl_xor(v, 2, 64);
        v += __shfl_xor(v, 4, 64); v += __shfl_xor(v, 8, 64);
        v += __shfl_xor(v, 16, 64);
        rsl[i] = v;
    }
    if (l31 == 0) {
        #pragma unroll
        for (int reg = 0; reg < 16; reg++) {
            int row = (reg & 3) + ((reg >> 2) << 3) + (l5 << 2);
            rsum[w][row] = rsl[reg];
        }
    }
    __syncthreads();
    float linv[16];
    #pragma unroll
    for (int reg = 0; reg < 16; reg++) {
        int row = (reg & 3) + ((reg >> 2) << 3) + (l5 << 2);
        linv[reg] = 1.f / (rsum[0][row] + rsum[1][row] + rsum[2][row] + rsum[3][row]);
    }
    // column sums: each lane owns column k0+kt*32+l31 for its 16 rows
    for (int kt = 0; kt < 8; kt++) {
        float c = 0.f;
        #pragma unroll
        for (int pr = 0; pr < 8; pr++) {
            unsigned int p = upk[kt][pr];
            c += bf2f((u16)(p & 0xffff)) * linv[2 * pr];
            c += bf2f((u16)(p >> 16))    * linv[2 * pr + 1];
        }
        c += __shfl_xor(c, 32, 64);
        if (l5 == 0) wcol[(w << 8) + (kt << 5) + l31] = c;
    }
    __syncthreads();
    float* wp = wpart + (((size_t)bl * HH + h) * 32 + qt) * TT;
    for (int cc = tid; cc < TT; cc += 256) wp[cc] = wcol[cc];
}

// ---------------------------------------------------------------------------
// sv: grid (64 bh, 4 kq). wl[k] = sum_qt wpart; partial sV over 256 k-rows.
// ---------------------------------------------------------------------------
__global__ __launch_bounds__(256) void sv_kernel(
    const float* __restrict__ x, const float* __restrict__ wpart, float* __restrict__ sVp)
{
    __shared__ float wl[256];
    int bh = blockIdx.x, kq = blockIdx.y, b = bh >> 3;
    int tid = threadIdx.x;
    float s = 0.f;
    for (int qtt = 0; qtt < 32; qtt++)
        s += wpart[((size_t)bh * 32 + qtt) * TT + (kq << 8) + tid];
    wl[tid] = s;
    __syncthreads();
    const float* xb = x + ((size_t)b * TT + (kq << 8)) * EE;
    float a0 = 0.f, a1 = 0.f;
    for (int k = 0; k < 256; k++) {
        float wk = wl[k];
        const float* xr = xb + (size_t)k * EE;
        a0 += wk * xr[tid];
        a1 += wk * xr[tid + 256];
    }
    sVp[((size_t)bh * 4 + kq) * EE + tid]       = a0;
    sVp[((size_t)bh * 4 + kq) * EE + tid + 256] = a1;
}

// ---------------------------------------------------------------------------
// out1: grid (64 bh, 4 ec), 128 thr. o1 = sV @ Wv[:,h-slice] + 1024*bv
// ---------------------------------------------------------------------------
__global__ __launch_bounds__(128) void out1_kernel(
    const float* __restrict__ sVp, const float* __restrict__ Wv,
    const float* __restrict__ bv, float* __restrict__ o1)
{
    __shared__ float s[512];
    int bh = blockIdx.x, ec = blockIdx.y, b = bh >> 3, h = bh & 7;
    int tid = threadIdx.x;
    for (int e = tid; e < 512; e += 128)
        s[e] = sVp[((size_t)bh * 4 + 0) * EE + e] + sVp[((size_t)bh * 4 + 1) * EE + e]
             + sVp[((size_t)bh * 4 + 2) * EE + e] + sVp[((size_t)bh * 4 + 3) * EE + e];
    __syncthreads();
    int col = (h << 9) + (ec << 7) + tid;
    float a0 = 0.f, a1 = 0.f, a2 = 0.f, a3 = 0.f;
    for (int e = 0; e < 512; e += 4) {
        a0 += s[e]     * Wv[(size_t)e * HEE + col];
        a1 += s[e + 1] * Wv[(size_t)(e + 1) * HEE + col];
        a2 += s[e + 2] * Wv[(size_t)(e + 2) * HEE + col];
        a3 += s[e + 3] * Wv[(size_t)(e + 3) * HEE + col];
    }
    o1[(size_t)b * HEE + col] = a0 + a1 + a2 + a3 + 1024.f * bv[col];
}

// ---------------------------------------------------------------------------
// out2 partial: grid (8 b, 16 jc), 512 thr. o2p = o1[jslice] @ Wu[jslice,:]
// ---------------------------------------------------------------------------
__global__ __launch_bounds__(512) void out2_kernel(
    const float* __restrict__ o1, const float* __restrict__ Wu, float* __restrict__ o2p)
{
    __shared__ float o1s[256];
    int b = blockIdx.x, jc = blockIdx.y;
    int tid = threadIdx.x;
    if (tid < 256) o1s[tid] = o1[(size_t)b * HEE + (jc << 8) + tid];
    __syncthreads();
    float a0 = 0.f, a1 = 0.f, a2 = 0.f, a3 = 0.f;
    const float* wu = Wu + (size_t)(jc << 8) * EE + tid;
    for (int j = 0; j < 256; j += 4) {
        a0 += o1s[j]     * wu[(size_t)j * EE];
        a1 += o1s[j + 1] * wu[(size_t)(j + 1) * EE];
        a2 += o1s[j + 2] * wu[(size_t)(j + 2) * EE];
        a3 += o1s[j + 3] * wu[(size_t)(j + 3) * EE];
    }
    o2p[((size_t)b * 16 + jc) * EE + tid] = a0 + a1 + a2 + a3;
}

// ---------------------------------------------------------------------------
// out2 reduce: grid 8, 512 thr. o2 = relu(sum_jc o2p + bu)
// ---------------------------------------------------------------------------
__global__ __launch_bounds__(512) void out2_reduce(
    const float* __restrict__ o2p, const float* __restrict__ bu, float* __restrict__ o2)
{
    int b = blockIdx.x, tid = threadIdx.x;
    float s = bu[tid];
    for (int jc = 0; jc < 16; jc++)
        s += o2p[((size_t)b * 16 + jc) * EE + tid];
    o2[(size_t)b * EE + tid] = fmaxf(s, 0.f);
}

// ---------------------------------------------------------------------------
// LN1 over rows of (x + out2 broadcast) -> y1 bf16
// ---------------------------------------------------------------------------
__global__ __launch_bounds__(256) void ln1_kernel(
    const float* __restrict__ x, const float* __restrict__ o2,
    const float* __restrict__ gg, const float* __restrict__ bb, u16* __restrict__ y)
{
    int row = blockIdx.x, b = row >> 10;
    int tid = threadIdx.x;
    const float* xr = x + (size_t)row * EE;
    const float* ob = o2 + (size_t)b * EE;
    float v0 = xr[tid] + ob[tid];
    float v1 = xr[tid + 256] + ob[tid + 256];
    float s = v0 + v1, q = v0 * v0 + v1 * v1;
    for (int off = 1; off < 64; off <<= 1) { s += __shfl_xor(s, off, 64); q += __shfl_xor(q, off, 64); }
    __shared__ float rs[4], rq[4];
    int w = tid >> 6, ln = tid & 63;
    if (ln == 0) { rs[w] = s; rq[w] = q; }
    __syncthreads();
    s = rs[0] + rs[1] + rs[2] + rs[3];
    q = rq[0] + rq[1] + rq[2] + rq[3];
    float mean = s * (1.f / EE);
    float var = q * (1.f / EE) - mean * mean;
    float rstd = rsqrtf(var + 1e-5f);
    y[(size_t)row * EE + tid]       = f2bf((v0 - mean) * rstd * gg[tid]       + bb[tid]);
    y[(size_t)row * EE + tid + 256] = f2bf((v1 - mean) * rstd * gg[tid + 256] + bb[tid + 256]);
}

// ---------------------------------------------------------------------------
// z = y1 + relu(y1 @ Wh + bh)   (128x128 tile GEMM, N=512), bf16 out
// ---------------------------------------------------------------------------
__global__ __launch_bounds__(256) void ffn_gemm(
    const u16* __restrict__ A, const u16* __restrict__ Wt,
    const float* __restrict__ bias, u16* __restrict__ Z)
{
    __shared__ u16 As[128][40];
    __shared__ u16 Bs[128][40];
    int tid = threadIdx.x;
    int n0 = blockIdx.x << 7, m0 = blockIdx.y << 7;
    int w = tid >> 6, lane = tid & 63;
    int g = lane >> 4, mn = lane & 15;
    int wm = (w >> 1) << 6, wn = (w & 1) << 6;
    floatx4 acc[4][4];
    floatx4 zero = {0.f, 0.f, 0.f, 0.f};
    for (int i = 0; i < 4; i++) for (int j = 0; j < 4; j++) acc[i][j] = zero;

    for (int kk = 0; kk < EE; kk += 32) {
        __syncthreads();
        for (int rep = 0; rep < 2; rep++) {
            int lin = tid + (rep << 8);
            int row = lin >> 2, c8 = (lin & 3) << 3;
            *(uint4*)&As[row][c8] = *(const uint4*)&A [(size_t)(m0 + row) * EE + kk + c8];
            *(uint4*)&Bs[row][c8] = *(const uint4*)&Wt[(size_t)(n0 + row) * EE + kk + c8];
        }
        __syncthreads();
        bf16x8 af[4], bfr[4];
        #pragma unroll
        for (int i = 0; i < 4; i++) af[i]  = *(const bf16x8*)&As[wm + (i << 4) + mn][g << 3];
        #pragma unroll
        for (int j = 0; j < 4; j++) bfr[j] = *(const bf16x8*)&Bs[wn + (j << 4) + mn][g << 3];
        #pragma unroll
        for (int i = 0; i < 4; i++)
            #pragma unroll
            for (int j = 0; j < 4; j++)
                acc[i][j] = __builtin_amdgcn_mfma_f32_16x16x32_bf16(af[i], bfr[j], acc[i][j], 0, 0, 0);
    }
    #pragma unroll
    for (int i = 0; i < 4; i++)
        #pragma unroll
        for (int j = 0; j < 4; j++) {
            int col = n0 + wn + (j << 4) + mn;
            float bv = bias[col];
            #pragma unroll
            for (int r = 0; r < 4; r++) {
                int row = m0 + wm + (i << 4) + (g << 2) + r;
                float v = fmaxf(acc[i][j][r] + bv, 0.f) + bf2f(A[(size_t)row * EE + col]);
                Z[(size_t)row * EE + col] = f2bf(v);
            }
        }
}

// ---------------------------------------------------------------------------
// LN2 over rows of z (bf16) -> d_out fp32
// ---------------------------------------------------------------------------
__global__ __launch_bounds__(256) void ln2_kernel(
    const u16* __restrict__ z, const float* __restrict__ gg,
    const float* __restrict__ bb, float* __restrict__ y)
{
    int row = blockIdx.x;
    int tid = threadIdx.x;
    const u16* zr = z + (size_t)row * EE;
    float v0 = bf2f(zr[tid]);
    float v1 = bf2f(zr[tid + 256]);
    float s = v0 + v1, q = v0 * v0 + v1 * v1;
    for (int off = 1; off < 64; off <<= 1) { s += __shfl_xor(s, off, 64); q += __shfl_xor(q, off, 64); }
    __shared__ float rs[4], rq[4];
    int w = tid >> 6, ln = tid & 63;
    if (ln == 0) { rs[w] = s; rq[w] = q; }
    __syncthreads();
    s = rs[0] + rs[1] + rs[2] + rs[3];
    q = rq[0] + rq[1] + rq[2] + rq[3];
    float mean = s * (1.f / EE);
    float var = q * (1.f / EE) - mean * mean;
    float rstd = rsqrtf(var + 1e-5f);
    y[(size_t)row * EE + tid]       = (v0 - mean) * rstd * gg[tid]       + bb[tid];
    y[(size_t)row * EE + tid + 256] = (v1 - mean) * rstd * gg[tid + 256] + bb[tid + 256];
}

// ---------------------------------------------------------------------------
extern "C" void kernel_launch(void* const* d_in, const int* in_sizes, int n_in,
                              void* d_out, int out_size, void* d_ws, size_t ws_size,
                              hipStream_t stream)
{
    const float* x  = (const float*)d_in[0];
    const float* Wq = (const float*)d_in[1];
    const float* bq = (const float*)d_in[2];
    const float* Wk = (const float*)d_in[3];
    const float* bk = (const float*)d_in[4];
    const float* Wv = (const float*)d_in[5];
    const float* bv = (const float*)d_in[6];
    const float* Wu = (const float*)d_in[7];
    const float* bu = (const float*)d_in[8];
    const float* g1 = (const float*)d_in[9];
    const float* b1 = (const float*)d_in[10];
    const float* Wh = (const float*)d_in[11];
    const float* bh = (const float*)d_in[12];
    const float* g2 = (const float*)d_in[13];
    const float* b2 = (const float*)d_in[14];
    float* out = (float*)d_out;

    // sizes
    const size_t szWtQ  = (size_t)HEE * EE * 2;            // 4 MB
    const size_t szWht  = (size_t)EE * EE * 2;             // 0.5 MB
    const size_t szXbf  = (size_t)BB * TT * EE * 2;        // 8 MB
    const size_t szQK1  = (size_t)HH * TT * EE * 2;        // 8 MB per batch
    const size_t szWp   = (size_t)BB * HH * 32 * TT * 4;   // 8 MB
    const size_t szSVp  = (size_t)BB * HH * 4 * EE * 4;    // 1 MB
    const size_t szO1   = (size_t)BB * HEE * 4;
    const size_t szO2p  = (size_t)BB * 16 * EE * 4;
    const size_t szO2   = (size_t)BB * EE * 4;
    const size_t fixedSz = 2 * szWtQ + szWht + szXbf + szWp + szSVp + szO1 + szO2p + szO2;
    // choose batching factor by workspace capacity (ws_size is constant -> same work every call)
    const size_t needFull = fixedSz + 2 * szQK1 * BB;
    int nb = (ws_size >= needFull + 1024) ? BB : 1;

    char* p = (char*)d_ws;
    u16* WtQ = (u16*)p;  p += szWtQ;
    u16* WtK = (u16*)p;  p += szWtQ;
    u16* Wht = (u16*)p;  p += szWht;
    u16* xbf = (u16*)p;  p += szXbf;
    float* wpart = (float*)p; p += szWp;
    float* sVp   = (float*)p; p += szSVp;
    float* o1    = (float*)p; p += szO1;
    float* o2p   = (float*)p; p += szO2p;
    float* o2    = (float*)p; p += szO2;
    u16* Qb  = (u16*)p;  p += szQK1 * nb;
    u16* Kb  = (u16*)p;  // p += szQK1 * nb;
    u16* y1 = Qb;   // overlay: Q dead after attention
    u16* zz = Kb;   // overlay: K dead after attention

    const float norm = 0.04419417382415922f;  // 1/sqrt(512)

    convx_kernel<<<dim3(2048), 256, 0, stream>>>(x, xbf);
    transpose_kernel<<<dim3(64, 8, 3), 256, 0, stream>>>(Wq, Wk, Wh, WtQ, WtK, Wht);
    for (int b0 = 0; b0 < BB; b0 += nb) {
        qk_proj<<<dim3(32, nb * 8, 2), 256, 0, stream>>>(
            xbf + (size_t)b0 * TT * EE, WtQ, WtK, bq, bk, Qb, Kb, norm);
        attn_kernel<<<dim3(32, 8, nb), 256, 0, stream>>>(
            Qb, Kb, wpart + (size_t)b0 * HH * 32 * TT);
    }
    sv_kernel<<<dim3(64, 4), 256, 0, stream>>>(x, wpart, sVp);
    out1_kernel<<<dim3(64, 4), 128, 0, stream>>>(sVp, Wv, bv, o1);
    out2_kernel<<<dim3(8, 16), 512, 0, stream>>>(o1, Wu, o2p);
    out2_reduce<<<dim3(8), 512, 0, stream>>>(o2p, bu, o2);
    ln1_kernel<<<dim3(8192), 256, 0, stream>>>(x, o2, g1, b1, y1);
    ffn_gemm<<<dim3(4, 64), 256, 0, stream>>>(y1, Wht, bh, zz);
    ln2_kernel<<<dim3(8192), 256, 0, stream>>>(zz, g2, b2, out);
}